// Round 2
// baseline (1015.609 us; speedup 1.0000x reference)
//
#include <hip/hip_runtime.h>

// VQ-VAE quantizer: h (256,512,32) fp32, embeddings (1024,32) fp32.
// Outputs concatenated in d_out (fp32): quantized_st [4194304] | indices [131072] | loss [131072]
//
// Correctness strategy: the harness compares indices against a numpy fp32
// reference. Near-tied candidates (top-2 gap < ulp(32) ~ 2e-6) are decided by
// the reference's OWN rounding, so we replicate it bit-for-bit:
//   f2  = numpy pairwise sum (8-acc stride-8, fixed combine tree) of fp32 squares
//   dot = BLAS-style sequential fmaf chain, k ascending (2.0 scaling is pow2-exact)
//   dist = fl(fl(f2 + e2[c]) - 2*dot), argmin with strict < (first occurrence)
// fp contract(off) prevents the compiler from re-fusing our mul/add bit pattern.

#define EMB_N 1024
#define DIM 32
#define NVEC (256 * 512)

__global__ void e2_kernel(const float* __restrict__ emb, float* __restrict__ e2) {
#pragma clang fp contract(off)
    int c = blockIdx.x * blockDim.x + threadIdx.x;
    if (c >= EMB_N) return;
    const float* e = emb + c * DIM;
    float sq[DIM];
#pragma unroll
    for (int i = 0; i < DIM; ++i) { float x = e[i]; sq[i] = x * x; }
    float r[8];
#pragma unroll
    for (int j = 0; j < 8; ++j)
        r[j] = ((sq[j] + sq[j + 8]) + sq[j + 16]) + sq[j + 24];
    e2[c] = ((r[0] + r[1]) + (r[2] + r[3])) + ((r[4] + r[5]) + (r[6] + r[7]));
}

__global__ __launch_bounds__(256) void vq_kernel(
    const float* __restrict__ h,
    const float* __restrict__ emb,
    const float* __restrict__ e2,
    float* __restrict__ out_q,     // NVEC*DIM
    float* __restrict__ out_idx,   // NVEC
    float* __restrict__ out_loss)  // NVEC
{
#pragma clang fp contract(off)
    const int t = blockIdx.x * blockDim.x + threadIdx.x;
    const int v = t >> 1;        // vector index (2 lanes per vector)
    const int half = t & 1;      // which 512-candidate half this lane scans
    const float* f = h + (size_t)v * DIM;

    // h row into registers
    float fr[DIM];
#pragma unroll
    for (int i = 0; i < DIM; i += 4) {
        float4 x = *(const float4*)(f + i);
        fr[i] = x.x; fr[i + 1] = x.y; fr[i + 2] = x.z; fr[i + 3] = x.w;
    }

    // ||f||^2 with numpy's exact pairwise order (n=32: 8 accs, stride 8, fixed tree)
    float sq[DIM];
#pragma unroll
    for (int i = 0; i < DIM; ++i) sq[i] = fr[i] * fr[i];
    float r[8];
#pragma unroll
    for (int j = 0; j < 8; ++j)
        r[j] = ((sq[j] + sq[j + 8]) + sq[j + 16]) + sq[j + 24];
    const float f2 = ((r[0] + r[1]) + (r[2] + r[3])) + ((r[4] + r[5]) + (r[6] + r[7]));

    // scan this lane's 512 candidates, 2 interleaved fma chains for ILP
    const int c0 = half * (EMB_N / 2);
    float best = 3.4e38f;
    int bidx = 0;
    for (int c = c0; c < c0 + EMB_N / 2; c += 2) {
        const float* e0 = emb + (size_t)c * DIM;   // wave-uniform -> scalar loads
        const float* e1 = e0 + DIM;
        float a0 = 0.f, a1 = 0.f;
#pragma unroll
        for (int k = 0; k < DIM; ++k) {
            a0 = __builtin_fmaf(fr[k], e0[k], a0);  // BLAS k-sequential fma chain
            a1 = __builtin_fmaf(fr[k], e1[k], a1);
        }
        float d0 = (f2 + e2[c])     - (2.0f * a0);  // fl(fl(f2+e2) - 2dot), 2*a exact
        float d1 = (f2 + e2[c + 1]) - (2.0f * a1);
        if (d0 < best) { best = d0; bidx = c; }     // strict <: first occurrence
        if (d1 < best) { best = d1; bidx = c + 1; }
    }

    // combine the two halves; ties -> low half (smaller index), matching np.argmin
    float ob = __shfl_xor(best, 1);
    int   oi = __shfl_xor(bidx, 1);
    const float loB = half ? ob : best;  const int loI = half ? oi : bidx;
    const float hiB = half ? best : ob;  const int hiI = half ? bidx : oi;
    const int widx = (hiB < loB) ? hiI : loI;

    // epilogue: each lane writes its 16 elements of quantized_st
    const float* q  = emb + (size_t)widx * DIM + half * 16;
    const float* fj = f + half * 16;   // reload from global (L1-hot) to avoid
                                       // dynamic register-array indexing
    float ps = 0.f;
#pragma unroll
    for (int i = 0; i < 16; i += 4) {
        float4 fx = *(const float4*)(fj + i);
        float4 qx; qx.x = q[i]; qx.y = q[i+1]; qx.z = q[i+2]; qx.w = q[i+3];
        float dx = qx.x - fx.x, dy = qx.y - fx.y, dz = qx.z - fx.z, dw = qx.w - fx.w;
        ps += dx * dx; ps += dy * dy; ps += dz * dz; ps += dw * dw;
        float4 o;
        o.x = fx.x + (qx.x - fx.x);
        o.y = fx.y + (qx.y - fx.y);
        o.z = fx.z + (qx.z - fx.z);
        o.w = fx.w + (qx.w - fx.w);
        *(float4*)(out_q + (size_t)v * DIM + half * 16 + i) = o;
    }
    float tot = ps + __shfl_xor(ps, 1);
    if (half == 0) {
        float m = tot * (1.0f / DIM);
        out_idx[v]  = (float)widx;
        out_loss[v] = m * 0.1f + m * 0.1f;
    }
}

extern "C" void kernel_launch(void* const* d_in, const int* in_sizes, int n_in,
                              void* d_out, int out_size, void* d_ws, size_t ws_size,
                              hipStream_t stream) {
    const float* h   = (const float*)d_in[0];
    const float* emb = (const float*)d_in[1];
    float* out = (float*)d_out;
    float* out_q    = out;                               // 4194304
    float* out_idx  = out + (size_t)NVEC * DIM;          // 131072
    float* out_loss = out + (size_t)NVEC * DIM + NVEC;   // 131072
    float* e2 = (float*)d_ws;                            // 1024 floats scratch

    e2_kernel<<<EMB_N / 256, 256, 0, stream>>>(emb, e2);
    vq_kernel<<<(NVEC * 2) / 256, 256, 0, stream>>>(h, emb, e2, out_q, out_idx, out_loss);
}

// Round 3
// 322.864 us; speedup vs baseline: 3.1456x; 3.1456x over previous
//
#include <hip/hip_runtime.h>

// VQ-VAE quantizer: h (256,512,32) fp32, embeddings (1024,32) fp32.
// Outputs concatenated in d_out (fp32): quantized_st [4194304] | indices [131072] | loss [131072]
//
// Bit-exactness vs numpy fp32 reference (required for argmin near-ties):
//   f2  = numpy pairwise sum (8-acc stride-8, fixed combine tree) of fp32 squares
//   dot = BLAS-style sequential fmaf chain, k ascending (2.0 scaling is pow2-exact)
//   dist = fl(fl(f2 + e2[c]) - 2*dot), argmin with strict < (first occurrence)
//   fp contract(off) so the compiler can't re-fuse and change bits.
//
// Perf: ONE THREAD PER VECTOR, candidate loop wave-uniform so embedding-row
// loads scalarize to s_load (SMEM) and the inner loop is pure VALU fma.
// (Round-2's lane-divergent split forced per-lane VMEM loads -> 985us, VALUBusy 14%.)

#define EMB_N 1024
#define DIM 32
#define NVEC (256 * 512)

__global__ void e2_kernel(const float* __restrict__ emb, float* __restrict__ e2) {
#pragma clang fp contract(off)
    int c = blockIdx.x * blockDim.x + threadIdx.x;
    if (c >= EMB_N) return;
    const float* e = emb + c * DIM;
    float sq[DIM];
#pragma unroll
    for (int i = 0; i < DIM; ++i) { float x = e[i]; sq[i] = x * x; }
    float r[8];
#pragma unroll
    for (int j = 0; j < 8; ++j)
        r[j] = ((sq[j] + sq[j + 8]) + sq[j + 16]) + sq[j + 24];
    e2[c] = ((r[0] + r[1]) + (r[2] + r[3])) + ((r[4] + r[5]) + (r[6] + r[7]));
}

__global__ __launch_bounds__(256) void vq_kernel(
    const float* __restrict__ h,
    const float* __restrict__ emb,
    const float* __restrict__ e2,
    float* __restrict__ out_q,     // NVEC*DIM
    float* __restrict__ out_idx,   // NVEC
    float* __restrict__ out_loss)  // NVEC
{
#pragma clang fp contract(off)
    const int v = blockIdx.x * blockDim.x + threadIdx.x;  // one thread per vector
    const float* f = h + (size_t)v * DIM;

    // h row into registers (coalesced float4 loads)
    float fr[DIM];
#pragma unroll
    for (int i = 0; i < DIM; i += 4) {
        float4 x = *(const float4*)(f + i);
        fr[i] = x.x; fr[i + 1] = x.y; fr[i + 2] = x.z; fr[i + 3] = x.w;
    }

    // ||f||^2 with numpy's exact pairwise order (n=32: 8 accs, stride 8, fixed tree)
    float sq[DIM];
#pragma unroll
    for (int i = 0; i < DIM; ++i) sq[i] = fr[i] * fr[i];
    float r[8];
#pragma unroll
    for (int j = 0; j < 8; ++j)
        r[j] = ((sq[j] + sq[j + 8]) + sq[j + 16]) + sq[j + 24];
    const float f2 = ((r[0] + r[1]) + (r[2] + r[3])) + ((r[4] + r[5]) + (r[6] + r[7]));

    // Wave-uniform candidate scan: every lane reads the SAME embedding row, so
    // the address is uniform -> scalar (SMEM) loads + v_fma with sgpr operand.
    float best = 3.4e38f;
    int bidx = 0;
#pragma unroll 2
    for (int c = 0; c < EMB_N; c += 2) {
        const float* e0 = emb + (size_t)c * DIM;   // uniform address
        const float* e1 = e0 + DIM;
        const float s0 = e2[c];                    // uniform
        const float s1 = e2[c + 1];
        float a0 = 0.f, a1 = 0.f;
#pragma unroll
        for (int k = 0; k < DIM; ++k) {
            a0 = __builtin_fmaf(fr[k], e0[k], a0);  // BLAS k-sequential fma chain
            a1 = __builtin_fmaf(fr[k], e1[k], a1);
        }
        float d0 = (f2 + s0) - (2.0f * a0);  // fl(fl(f2+e2) - 2*dot); 2*a exact
        float d1 = (f2 + s1) - (2.0f * a1);
        if (d0 < best) { best = d0; bidx = c; }     // strict <: first occurrence
        if (d1 < best) { best = d1; bidx = c + 1; }
    }

    // Epilogue: gather winner row (divergent, L2-hot), write quantized_st and loss.
    const float* q = emb + (size_t)bidx * DIM;
    float ps = 0.f;
#pragma unroll
    for (int i = 0; i < DIM; i += 4) {
        float4 fx; fx.x = fr[i]; fx.y = fr[i+1]; fx.z = fr[i+2]; fx.w = fr[i+3];
        float4 qx; qx.x = q[i]; qx.y = q[i+1]; qx.z = q[i+2]; qx.w = q[i+3];
        float dx = qx.x - fx.x, dy = qx.y - fx.y, dz = qx.z - fx.z, dw = qx.w - fx.w;
        ps += dx * dx; ps += dy * dy; ps += dz * dz; ps += dw * dw;
        float4 o;
        o.x = fx.x + (qx.x - fx.x);
        o.y = fx.y + (qx.y - fx.y);
        o.z = fx.z + (qx.z - fx.z);
        o.w = fx.w + (qx.w - fx.w);
        *(float4*)(out_q + (size_t)v * DIM + i) = o;
    }
    float m = ps * (1.0f / DIM);
    out_idx[v]  = (float)bidx;
    out_loss[v] = m * 0.1f + m * 0.1f;
}

extern "C" void kernel_launch(void* const* d_in, const int* in_sizes, int n_in,
                              void* d_out, int out_size, void* d_ws, size_t ws_size,
                              hipStream_t stream) {
    const float* h   = (const float*)d_in[0];
    const float* emb = (const float*)d_in[1];
    float* out = (float*)d_out;
    float* out_q    = out;                               // 4194304
    float* out_idx  = out + (size_t)NVEC * DIM;          // 131072
    float* out_loss = out + (size_t)NVEC * DIM + NVEC;   // 131072
    float* e2 = (float*)d_ws;                            // 1024 floats scratch

    e2_kernel<<<EMB_N / 256, 256, 0, stream>>>(emb, e2);
    vq_kernel<<<NVEC / 256, 256, 0, stream>>>(h, emb, e2, out_q, out_idx, out_loss);
}

// Round 4
// 240.340 us; speedup vs baseline: 4.2257x; 1.3434x over previous
//
#include <hip/hip_runtime.h>

// VQ-VAE quantizer: h (256,512,32) fp32, embeddings (1024,32) fp32.
// Outputs concatenated in d_out (fp32): quantized_st [4194304] | indices [131072] | loss [131072]
//
// Bit-exactness vs numpy fp32 reference (required for argmin near-ties):
//   f2  = numpy pairwise sum (8-acc stride-8, fixed combine tree) of fp32 squares
//   dot = BLAS-style sequential fmaf chain, k ascending (2.0 scaling is pow2-exact)
//   dist = fl(fl(f2 + e2[c]) - 2*dot), argmin with strict < (first occurrence)
//   fp contract(off) so the compiler can't re-fuse and change bits.
//
// Perf history:
//   R2: lane-divergent candidate split -> per-lane VMEM loads, 985us, VALUBusy 14%.
//   R3: wave-uniform scan, s_load scalarized -> 270us, but VALUBusy 52% because
//       one-thread-per-vector caps the grid at 2048 waves (2/SIMD, occ 23%):
//       scalar-cache-miss latency (~200cyc to L2 for the 128KB table) can't hide.
//   R4 (this): 4-way candidate split across blockIdx.y (block-uniform -> still
//       scalarized), 8192 waves = 32/CU full occupancy. Partials as u64 keys
//       (enc(dist)<<32 | idx), min in a final pass == first-occurrence argmin.

#define EMB_N 1024
#define DIM 32
#define NVEC (256 * 512)
#define SPLIT 4
#define CAND_PER (EMB_N / SPLIT)

typedef unsigned long long u64;
typedef unsigned int u32;

__device__ __forceinline__ u32 enc_f32(float x) {
    u32 u = __float_as_uint(x);
    return (u & 0x80000000u) ? ~u : (u | 0x80000000u);  // monotone order-preserving
}

__global__ void e2_kernel(const float* __restrict__ emb, float* __restrict__ e2) {
#pragma clang fp contract(off)
    int c = blockIdx.x * blockDim.x + threadIdx.x;
    if (c >= EMB_N) return;
    const float* e = emb + c * DIM;
    float sq[DIM];
#pragma unroll
    for (int i = 0; i < DIM; ++i) { float x = e[i]; sq[i] = x * x; }
    float r[8];
#pragma unroll
    for (int j = 0; j < 8; ++j)
        r[j] = ((sq[j] + sq[j + 8]) + sq[j + 16]) + sq[j + 24];
    e2[c] = ((r[0] + r[1]) + (r[2] + r[3])) + ((r[4] + r[5]) + (r[6] + r[7]));
}

// ---------- split scan: each block handles 256 vectors x 256 candidates ----------
__global__ __launch_bounds__(256) void vq_scan(
    const float* __restrict__ h,
    const float* __restrict__ emb,
    const float* __restrict__ e2,
    u64* __restrict__ part)            // [SPLIT][NVEC]
{
#pragma clang fp contract(off)
    const int v  = blockIdx.x * blockDim.x + threadIdx.x;
    const int c0 = blockIdx.y * CAND_PER;          // block-uniform -> wave-uniform
    const float* f = h + (size_t)v * DIM;

    float fr[DIM];
#pragma unroll
    for (int i = 0; i < DIM; i += 4) {
        float4 x = *(const float4*)(f + i);
        fr[i] = x.x; fr[i + 1] = x.y; fr[i + 2] = x.z; fr[i + 3] = x.w;
    }

    // ||f||^2, numpy pairwise order (identical bits in every split)
    float sq[DIM];
#pragma unroll
    for (int i = 0; i < DIM; ++i) sq[i] = fr[i] * fr[i];
    float r[8];
#pragma unroll
    for (int j = 0; j < 8; ++j)
        r[j] = ((sq[j] + sq[j + 8]) + sq[j + 16]) + sq[j + 24];
    const float f2 = ((r[0] + r[1]) + (r[2] + r[3])) + ((r[4] + r[5]) + (r[6] + r[7]));

    float best = 3.4e38f;
    int bidx = c0;
#pragma unroll 2
    for (int c = c0; c < c0 + CAND_PER; c += 2) {
        const float* e0 = emb + (size_t)c * DIM;   // uniform address -> s_load
        const float* e1 = e0 + DIM;
        const float s0 = e2[c];
        const float s1 = e2[c + 1];
        float a0 = 0.f, a1 = 0.f;
#pragma unroll
        for (int k = 0; k < DIM; ++k) {
            a0 = __builtin_fmaf(fr[k], e0[k], a0);  // BLAS k-sequential fma chain
            a1 = __builtin_fmaf(fr[k], e1[k], a1);
        }
        float d0 = (f2 + s0) - (2.0f * a0);
        float d1 = (f2 + s1) - (2.0f * a1);
        if (d0 < best) { best = d0; bidx = c; }     // strict <: first occurrence
        if (d1 < best) { best = d1; bidx = c + 1; }
    }

    part[(size_t)blockIdx.y * NVEC + v] = ((u64)enc_f32(best) << 32) | (u32)bidx;
}

// ---------- final: min over splits, gather winner, write outputs ----------
__global__ __launch_bounds__(256) void vq_final(
    const float* __restrict__ h,
    const float* __restrict__ emb,
    const u64* __restrict__ part,
    float* __restrict__ out_q,
    float* __restrict__ out_idx,
    float* __restrict__ out_loss)
{
#pragma clang fp contract(off)
    const int v = blockIdx.x * blockDim.x + threadIdx.x;
    u64 k = part[v];
#pragma unroll
    for (int s = 1; s < SPLIT; ++s) {
        u64 ks = part[(size_t)s * NVEC + v];
        if (ks < k) k = ks;       // u64 min: dist first, then smaller idx (tie)
    }
    const int bidx = (int)(k & 0xFFFFFFFFu);

    const float* f = h + (size_t)v * DIM;
    const float* q = emb + (size_t)bidx * DIM;
    float ps = 0.f;
#pragma unroll
    for (int i = 0; i < DIM; i += 4) {
        float4 fx = *(const float4*)(f + i);
        float4 qx; qx.x = q[i]; qx.y = q[i+1]; qx.z = q[i+2]; qx.w = q[i+3];
        float dx = qx.x - fx.x, dy = qx.y - fx.y, dz = qx.z - fx.z, dw = qx.w - fx.w;
        ps += dx * dx; ps += dy * dy; ps += dz * dz; ps += dw * dw;
        float4 o;
        o.x = fx.x + (qx.x - fx.x);
        o.y = fx.y + (qx.y - fx.y);
        o.z = fx.z + (qx.z - fx.z);
        o.w = fx.w + (qx.w - fx.w);
        *(float4*)(out_q + (size_t)v * DIM + i) = o;
    }
    float m = ps * (1.0f / DIM);
    out_idx[v]  = (float)bidx;
    out_loss[v] = m * 0.1f + m * 0.1f;
}

// ---------- fallback (round-3 single kernel) if workspace is too small ----------
__global__ __launch_bounds__(256) void vq_kernel(
    const float* __restrict__ h,
    const float* __restrict__ emb,
    const float* __restrict__ e2,
    float* __restrict__ out_q,
    float* __restrict__ out_idx,
    float* __restrict__ out_loss)
{
#pragma clang fp contract(off)
    const int v = blockIdx.x * blockDim.x + threadIdx.x;
    const float* f = h + (size_t)v * DIM;
    float fr[DIM];
#pragma unroll
    for (int i = 0; i < DIM; i += 4) {
        float4 x = *(const float4*)(f + i);
        fr[i] = x.x; fr[i + 1] = x.y; fr[i + 2] = x.z; fr[i + 3] = x.w;
    }
    float sq[DIM];
#pragma unroll
    for (int i = 0; i < DIM; ++i) sq[i] = fr[i] * fr[i];
    float r[8];
#pragma unroll
    for (int j = 0; j < 8; ++j)
        r[j] = ((sq[j] + sq[j + 8]) + sq[j + 16]) + sq[j + 24];
    const float f2 = ((r[0] + r[1]) + (r[2] + r[3])) + ((r[4] + r[5]) + (r[6] + r[7]));
    float best = 3.4e38f;
    int bidx = 0;
#pragma unroll 2
    for (int c = 0; c < EMB_N; c += 2) {
        const float* e0 = emb + (size_t)c * DIM;
        const float* e1 = e0 + DIM;
        const float s0 = e2[c];
        const float s1 = e2[c + 1];
        float a0 = 0.f, a1 = 0.f;
#pragma unroll
        for (int k = 0; k < DIM; ++k) {
            a0 = __builtin_fmaf(fr[k], e0[k], a0);
            a1 = __builtin_fmaf(fr[k], e1[k], a1);
        }
        float d0 = (f2 + s0) - (2.0f * a0);
        float d1 = (f2 + s1) - (2.0f * a1);
        if (d0 < best) { best = d0; bidx = c; }
        if (d1 < best) { best = d1; bidx = c + 1; }
    }
    const float* q = emb + (size_t)bidx * DIM;
    float ps = 0.f;
#pragma unroll
    for (int i = 0; i < DIM; i += 4) {
        float4 fx; fx.x = fr[i]; fx.y = fr[i+1]; fx.z = fr[i+2]; fx.w = fr[i+3];
        float4 qx; qx.x = q[i]; qx.y = q[i+1]; qx.z = q[i+2]; qx.w = q[i+3];
        float dx = qx.x - fx.x, dy = qx.y - fx.y, dz = qx.z - fx.z, dw = qx.w - fx.w;
        ps += dx * dx; ps += dy * dy; ps += dz * dz; ps += dw * dw;
        float4 o;
        o.x = fx.x + (qx.x - fx.x);
        o.y = fx.y + (qx.y - fx.y);
        o.z = fx.z + (qx.z - fx.z);
        o.w = fx.w + (qx.w - fx.w);
        *(float4*)(out_q + (size_t)v * DIM + i) = o;
    }
    float m = ps * (1.0f / DIM);
    out_idx[v]  = (float)bidx;
    out_loss[v] = m * 0.1f + m * 0.1f;
}

extern "C" void kernel_launch(void* const* d_in, const int* in_sizes, int n_in,
                              void* d_out, int out_size, void* d_ws, size_t ws_size,
                              hipStream_t stream) {
    const float* h   = (const float*)d_in[0];
    const float* emb = (const float*)d_in[1];
    float* out = (float*)d_out;
    float* out_q    = out;                               // 4194304
    float* out_idx  = out + (size_t)NVEC * DIM;          // 131072
    float* out_loss = out + (size_t)NVEC * DIM + NVEC;   // 131072

    float* e2  = (float*)d_ws;                           // 1024 floats (4 KB)
    u64*  part = (u64*)((char*)d_ws + 8192);             // SPLIT*NVEC u64 (4 MB)
    const size_t need = 8192 + (size_t)SPLIT * NVEC * sizeof(u64);

    e2_kernel<<<EMB_N / 256, 256, 0, stream>>>(emb, e2);
    if (ws_size >= need) {
        dim3 grid(NVEC / 256, SPLIT);
        vq_scan<<<grid, 256, 0, stream>>>(h, emb, e2, part);
        vq_final<<<NVEC / 256, 256, 0, stream>>>(h, emb, part, out_q, out_idx, out_loss);
    } else {
        vq_kernel<<<NVEC / 256, 256, 0, stream>>>(h, emb, e2, out_q, out_idx, out_loss);
    }
}

// Round 5
// 193.446 us; speedup vs baseline: 5.2501x; 1.2424x over previous
//
#include <hip/hip_runtime.h>

// VQ-VAE quantizer: h (256,512,32) fp32, embeddings (1024,32) fp32.
// Outputs concatenated in d_out (fp32): quantized_st [4194304] | indices [131072] | loss [131072]
//
// Bit-exactness vs numpy fp32 reference (required for argmin near-ties):
//   f2  = numpy pairwise sum (8-acc stride-8, fixed combine tree) of fp32 squares
//   dot = BLAS-style sequential fmaf chain, k ascending (2.0 scaling is pow2-exact)
//   dist = fl(fl(f2 + e2[c]) - 2*dot), argmin with strict < (first occurrence)
//   fp contract(off) so the compiler can't re-fuse and change bits.
//
// Perf history:
//   R2: lane-divergent split -> per-lane VMEM, 985us, VALUBusy 14%.
//   R3: wave-uniform scan (s_load scalarized) -> 270us, VALUBusy 52%, occ 23%.
//   R4: 4-way candidate split -> 240us; scan 170us @ VALUBusy 82% BUT ~82 VALU
//       instrs/candidate vs 35 expected: unroll-2 keeps 128 sgpr values live,
//       SGPR pressure (112 alloc) forces s->v copies (~1 v_mov per element).
//   R5 (this): 2 h-rows per thread (each s_load feeds 2 fmas, 2 indep chains),
//       unroll 1 (32 sgprs live), SPLIT=8 to keep 8192 waves.

#define EMB_N 1024
#define DIM 32
#define NVEC (256 * 512)
#define HALFV (NVEC / 2)

typedef unsigned long long u64;
typedef unsigned int u32;

__device__ __forceinline__ u32 enc_f32(float x) {
    u32 u = __float_as_uint(x);
    return (u & 0x80000000u) ? ~u : (u | 0x80000000u);  // monotone order-preserving
}

__global__ void e2_kernel(const float* __restrict__ emb, float* __restrict__ e2) {
#pragma clang fp contract(off)
    int c = blockIdx.x * blockDim.x + threadIdx.x;
    if (c >= EMB_N) return;
    const float* e = emb + c * DIM;
    float sq[DIM];
#pragma unroll
    for (int i = 0; i < DIM; ++i) { float x = e[i]; sq[i] = x * x; }
    float r[8];
#pragma unroll
    for (int j = 0; j < 8; ++j)
        r[j] = ((sq[j] + sq[j + 8]) + sq[j + 16]) + sq[j + 24];
    e2[c] = ((r[0] + r[1]) + (r[2] + r[3])) + ((r[4] + r[5]) + (r[6] + r[7]));
}

// numpy pairwise ||x||^2 for n=32: 8 accumulators stride 8, fixed combine tree
__device__ __forceinline__ float norm2_np(const float* fr) {
    float sq[DIM];
#pragma unroll
    for (int i = 0; i < DIM; ++i) sq[i] = fr[i] * fr[i];
    float r[8];
#pragma unroll
    for (int j = 0; j < 8; ++j)
        r[j] = ((sq[j] + sq[j + 8]) + sq[j + 16]) + sq[j + 24];
    return ((r[0] + r[1]) + (r[2] + r[3])) + ((r[4] + r[5]) + (r[6] + r[7]));
}

// ---------- split scan: 2 h-rows per thread, CPER candidates per block ----------
template <int CPER>
__global__ __launch_bounds__(256) void vq_scan2(
    const float* __restrict__ h,
    const float* __restrict__ emb,
    const float* __restrict__ e2,
    u64* __restrict__ part)            // [nsplit][NVEC]
{
#pragma clang fp contract(off)
    const int t  = blockIdx.x * blockDim.x + threadIdx.x;  // 0..HALFV
    const int v0 = t;                 // row A
    const int v1 = t + HALFV;         // row B
    const int c0 = blockIdx.y * CPER; // block-uniform -> wave-uniform

    float fr0[DIM], fr1[DIM];
#pragma unroll
    for (int i = 0; i < DIM; i += 4) {
        float4 x = *(const float4*)(h + (size_t)v0 * DIM + i);
        fr0[i] = x.x; fr0[i + 1] = x.y; fr0[i + 2] = x.z; fr0[i + 3] = x.w;
        float4 y = *(const float4*)(h + (size_t)v1 * DIM + i);
        fr1[i] = y.x; fr1[i + 1] = y.y; fr1[i + 2] = y.z; fr1[i + 3] = y.w;
    }
    const float f20 = norm2_np(fr0);
    const float f21 = norm2_np(fr1);

    float best0 = 3.4e38f, best1 = 3.4e38f;
    int bi0 = c0, bi1 = c0;
#pragma unroll 1
    for (int c = c0; c < c0 + CPER; ++c) {
        const float* e = emb + (size_t)c * DIM;   // uniform -> s_load, 32 sgprs live
        const float  s = e2[c];
        float a0 = 0.f, a1 = 0.f;
#pragma unroll
        for (int k = 0; k < DIM; ++k) {
            float ek = e[k];
            a0 = __builtin_fmaf(fr0[k], ek, a0);  // BLAS k-sequential chain, row A
            a1 = __builtin_fmaf(fr1[k], ek, a1);  // row B (independent chain = ILP)
        }
        float d0 = (f20 + s) - (2.0f * a0);  // fl(fl(f2+e2)-2dot); 2*a exact
        float d1 = (f21 + s) - (2.0f * a1);
        if (d0 < best0) { best0 = d0; bi0 = c; }  // strict <: first occurrence
        if (d1 < best1) { best1 = d1; bi1 = c; }
    }

    u64* p = part + (size_t)blockIdx.y * NVEC;
    p[v0] = ((u64)enc_f32(best0) << 32) | (u32)bi0;
    p[v1] = ((u64)enc_f32(best1) << 32) | (u32)bi1;
}

// ---------- final: min over splits, gather winner, write outputs ----------
__global__ __launch_bounds__(256) void vq_final(
    const float* __restrict__ h,
    const float* __restrict__ emb,
    const u64* __restrict__ part,
    int nsplit,
    float* __restrict__ out_q,
    float* __restrict__ out_idx,
    float* __restrict__ out_loss)
{
#pragma clang fp contract(off)
    const int v = blockIdx.x * blockDim.x + threadIdx.x;
    u64 k = part[v];
    for (int s = 1; s < nsplit; ++s) {
        u64 ks = part[(size_t)s * NVEC + v];
        if (ks < k) k = ks;       // u64 min: dist first, then smaller idx (tie)
    }
    const int bidx = (int)(k & 0xFFFFFFFFu);

    const float* f = h + (size_t)v * DIM;
    const float* q = emb + (size_t)bidx * DIM;
    float ps = 0.f;
#pragma unroll
    for (int i = 0; i < DIM; i += 4) {
        float4 fx = *(const float4*)(f + i);
        float4 qx; qx.x = q[i]; qx.y = q[i+1]; qx.z = q[i+2]; qx.w = q[i+3];
        float dx = qx.x - fx.x, dy = qx.y - fx.y, dz = qx.z - fx.z, dw = qx.w - fx.w;
        ps += dx * dx; ps += dy * dy; ps += dz * dz; ps += dw * dw;
        float4 o;
        o.x = fx.x + (qx.x - fx.x);
        o.y = fx.y + (qx.y - fx.y);
        o.z = fx.z + (qx.z - fx.z);
        o.w = fx.w + (qx.w - fx.w);
        *(float4*)(out_q + (size_t)v * DIM + i) = o;
    }
    float m = ps * (1.0f / DIM);
    out_idx[v]  = (float)bidx;
    out_loss[v] = m * 0.1f + m * 0.1f;
}

// ---------- fallback (round-3 single kernel) if workspace is too small ----------
__global__ __launch_bounds__(256) void vq_kernel(
    const float* __restrict__ h,
    const float* __restrict__ emb,
    const float* __restrict__ e2,
    float* __restrict__ out_q,
    float* __restrict__ out_idx,
    float* __restrict__ out_loss)
{
#pragma clang fp contract(off)
    const int v = blockIdx.x * blockDim.x + threadIdx.x;
    const float* f = h + (size_t)v * DIM;
    float fr[DIM];
#pragma unroll
    for (int i = 0; i < DIM; i += 4) {
        float4 x = *(const float4*)(f + i);
        fr[i] = x.x; fr[i + 1] = x.y; fr[i + 2] = x.z; fr[i + 3] = x.w;
    }
    const float f2 = norm2_np(fr);
    float best = 3.4e38f;
    int bidx = 0;
#pragma unroll 1
    for (int c = 0; c < EMB_N; ++c) {
        const float* e = emb + (size_t)c * DIM;
        const float s = e2[c];
        float a0 = 0.f;
#pragma unroll
        for (int k = 0; k < DIM; ++k) a0 = __builtin_fmaf(fr[k], e[k], a0);
        float d0 = (f2 + s) - (2.0f * a0);
        if (d0 < best) { best = d0; bidx = c; }
    }
    const float* q = emb + (size_t)bidx * DIM;
    float ps = 0.f;
#pragma unroll
    for (int i = 0; i < DIM; i += 4) {
        float4 fx; fx.x = fr[i]; fx.y = fr[i+1]; fx.z = fr[i+2]; fx.w = fr[i+3];
        float4 qx; qx.x = q[i]; qx.y = q[i+1]; qx.z = q[i+2]; qx.w = q[i+3];
        float dx = qx.x - fx.x, dy = qx.y - fx.y, dz = qx.z - fx.z, dw = qx.w - fx.w;
        ps += dx * dx; ps += dy * dy; ps += dz * dz; ps += dw * dw;
        float4 o;
        o.x = fx.x + (qx.x - fx.x);
        o.y = fx.y + (qx.y - fx.y);
        o.z = fx.z + (qx.z - fx.z);
        o.w = fx.w + (qx.w - fx.w);
        *(float4*)(out_q + (size_t)v * DIM + i) = o;
    }
    float m = ps * (1.0f / DIM);
    out_idx[v]  = (float)bidx;
    out_loss[v] = m * 0.1f + m * 0.1f;
}

extern "C" void kernel_launch(void* const* d_in, const int* in_sizes, int n_in,
                              void* d_out, int out_size, void* d_ws, size_t ws_size,
                              hipStream_t stream) {
    const float* h   = (const float*)d_in[0];
    const float* emb = (const float*)d_in[1];
    float* out = (float*)d_out;
    float* out_q    = out;                               // 4194304
    float* out_idx  = out + (size_t)NVEC * DIM;          // 131072
    float* out_loss = out + (size_t)NVEC * DIM + NVEC;   // 131072

    float* e2  = (float*)d_ws;                           // 1024 floats (4 KB)
    u64*  part = (u64*)((char*)d_ws + 8192);
    const size_t need8 = 8192 + 8ull * NVEC * sizeof(u64);  // ~8.4 MB
    const size_t need4 = 8192 + 4ull * NVEC * sizeof(u64);  // ~4.2 MB

    e2_kernel<<<EMB_N / 256, 256, 0, stream>>>(emb, e2);
    if (ws_size >= need8) {
        dim3 grid(HALFV / 256, 8);
        vq_scan2<EMB_N / 8><<<grid, 256, 0, stream>>>(h, emb, e2, part);
        vq_final<<<NVEC / 256, 256, 0, stream>>>(h, emb, part, 8, out_q, out_idx, out_loss);
    } else if (ws_size >= need4) {
        dim3 grid(HALFV / 256, 4);
        vq_scan2<EMB_N / 4><<<grid, 256, 0, stream>>>(h, emb, e2, part);
        vq_final<<<NVEC / 256, 256, 0, stream>>>(h, emb, part, 4, out_q, out_idx, out_loss);
    } else {
        vq_kernel<<<NVEC / 256, 256, 0, stream>>>(h, emb, e2, out_q, out_idx, out_loss);
    }
}